// Round 15
// baseline (3812.440 us; speedup 1.0000x reference)
//
#include <hip/hip_runtime.h>
#include <stdint.h>

#define CIN 768
#define CMID 512
#define NPIX 4096
#define NANCH 49152
#define NBATCH 4
#define PRE_NMS_N 6000
#define POST_NMS_N 300

// ---------------- zero scratch (hist + counters) ----------------
__global__ void zeroK(uint32_t* __restrict__ p, int nWords){
  int i = blockIdx.x * 256 + threadIdx.x;
  if (i < nWords) p[i] = 0u;
}

// ---------------- conv 3x3, 768->512, bias, relu ----------------
// v11 = r8 numerics bit-for-bit (fp64 masters, drains at ic%4==3, per-output
// fma order (ic,ky,kx), same epilogue) with features staged in 4-ic
// half-chunks so LDS data = 9216+480 floats = 38784 B -> granule 38912:
//  * 4 x 38912 = 155648 <= 163840 (8 KB driver slack) -> 4 blocks/CU resident
//    (r11: 40960-granule x4 = exact capacity -> stuck at 3 blocks).
//  * LDS-limit occupancy = 4 blocks -> LLVM reg budget 128 = r8's proven
//    no-spill allocation (r2: budget 64 -> spill; r8: budget 168, used 128).
//  * 16 waves/CU (4/SIMD) for FMA(737us/SIMD) || LDS(1014us/CU) overlap that
//    r8's 12 waves failed to achieve (1780 ~= 737+1014 serialized).
// Spill sentinels: FETCH ~300 MB, WRITE ~33 MB.
__global__ __launch_bounds__(256) void conv3x3K(
    const float* __restrict__ feat, const float* __restrict__ W1,
    const float* __restrict__ b1, float* __restrict__ xout){
  __shared__ float wLds[9216];   // [ic 0..7][ky 0..2][g 0..31][q*3+kx]
  __shared__ float fLds[480];    // [ic 0..3][row 0..9][12], col c <-> x = tx0+c-1
  const int tid = threadIdx.x;
  const int g  = tid >> 3;       // oc-quad 0..31
  const int py = tid & 7;        // output row 0..7
  const int ty0 = (blockIdx.x >> 3) << 3;
  const int tx0 = (blockIdx.x & 7) << 3;
  const int ocb = blockIdx.y << 7;   // 128 oc per block
  const int b = blockIdx.z;

  // ---- weight staging consts: thread stages 36 contiguous floats ----
  const int oc_t  = tid >> 1;        // 0..127
  const int halfw = tid & 1;         // ic_local 0..3 or 4..7
  const float* wsrc0 = W1 + (size_t)(ocb + oc_t)*6912 + halfw*36;
  const int gq   = (oc_t>>2)*12 + (oc_t&3)*3;   // g*12 + q*3
  const int icl0 = halfw << 2;                  // ic_local base

  // ---- feature staging consts: 4 ic x 10 rows x 10 cols = 400 / half-chunk ----
  int fdst[2]; int fsrc[2]; bool fgo[2]; bool fact[2];
#pragma unroll
  for (int i=0;i<2;i++){
    int lin = tid + (i<<8);
    fact[i] = lin < 400;
    int l2 = fact[i] ? lin : 0;
    int ic = l2/100; int r2 = l2 - ic*100;
    int row = r2/10; int col = r2 - row*10;
    int gy = ty0 + row - 1, gx = tx0 + col - 1;
    fgo[i]  = fact[i] && gy>=0 && gy<64 && gx>=0 && gx<64;
    fdst[i] = ic*120 + row*12 + col;
    fsrc[i] = (ic<<12) + (gy<<6) + gx;
  }
  const float* fbase = feat + ((size_t)(b*CIN) << 12);

  double macc[4][8];
  float cacc[4][8];
#pragma unroll
  for (int q=0;q<4;q++)
#pragma unroll
    for (int j=0;j<8;j++){ macc[q][j]=0.0; cacc[q][j]=0.0f; }

  for (int icb = 0; icb < CIN; icb += 8){
    // ---- stage weights (8 ic): 36 contiguous src floats -> [ic][ky][g][q*3+kx] ----
    {
      const float* s = wsrc0 + (size_t)icb*9;
      float w0[36];
#pragma unroll
      for (int m=0;m<9;m++){
        float4 v = *reinterpret_cast<const float4*>(s + (m<<2));
        w0[4*m+0]=v.x; w0[4*m+1]=v.y; w0[4*m+2]=v.z; w0[4*m+3]=v.w;
      }
#pragma unroll
      for (int r=0;r<4;r++)
#pragma unroll
        for (int k=0;k<9;k++)
          wLds[(icl0+r)*1152 + (k/3)*384 + gq + (k%3)] = w0[r*9+k];
    }
    // ---- two half-chunks of 4 ic each: stage features, compute ----
#pragma unroll
    for (int half=0; half<2; half++){
      const int icb4 = icb + (half<<2);
#pragma unroll
      for (int i=0;i<2;i++){
        if (fact[i]){
          float v = 0.0f;
          if (fgo[i]) v = fbase[((size_t)icb4 << 12) + fsrc[i]];
          fLds[fdst[i]] = v;
        }
      }
      __syncthreads();
#pragma unroll
      for (int ic2=0; ic2<4; ic2++){
        const int icg = (half<<2) + ic2;           // 0..7 within weight chunk
        const float* fb = &fLds[ic2*120 + py*12];
        const float* wb = &wLds[icg*1152 + g*12];
#pragma unroll
        for (int ky=0;ky<3;ky++){
          float4 a = *reinterpret_cast<const float4*>(fb + ky*12);
          float4 c = *reinterpret_cast<const float4*>(fb + ky*12 + 4);
          float2 e = *reinterpret_cast<const float2*>(fb + ky*12 + 8);
          const float f[10] = {a.x,a.y,a.z,a.w,c.x,c.y,c.z,c.w,e.x,e.y};
          const float* wp = wb + ky*384;
          float4 wa = *reinterpret_cast<const float4*>(wp);
          float4 wv = *reinterpret_cast<const float4*>(wp+4);
          float4 wc = *reinterpret_cast<const float4*>(wp+8);
          const float w12[12] = {wa.x,wa.y,wa.z,wa.w, wv.x,wv.y,wv.z,wv.w,
                                 wc.x,wc.y,wc.z,wc.w};
#pragma unroll
          for (int q=0;q<4;q++)
#pragma unroll
            for (int kx=0;kx<3;kx++){
              float we = w12[q*3+kx];
#pragma unroll
              for (int j=0;j<8;j++)
                cacc[q][j] = fmaf(we, f[j+kx], cacc[q][j]);
            }
        }
        if (ic2 == 3){   // global ic%4==3: end of each 4-ic half-chunk
#pragma unroll
          for (int q=0;q<4;q++)
#pragma unroll
            for (int j=0;j<8;j++){ macc[q][j] += (double)cacc[q][j]; cacc[q][j]=0.0f; }
        }
      }
      __syncthreads();
    }
  }
#pragma unroll
  for (int q=0;q<4;q++){
    float bias = b1[ocb + (g<<2) + q];
    float4 ov;
    float* o = (float*)&ov;
#pragma unroll
    for (int j=0;j<4;j++){
      float v = __fadd_rn((float)macc[q][j], bias);
      o[j] = fmaxf(v, 0.0f);
    }
    *reinterpret_cast<float4*>(
      &xout[((size_t)(b*CMID + ocb + (g<<2) + q) << 12) + ((ty0+py) << 6) + tx0]) = ov;
    float4 ov2;
    float* o2 = (float*)&ov2;
#pragma unroll
    for (int j=0;j<4;j++){
      float v = __fadd_rn((float)macc[q][j+4], bias);
      o2[j] = fmaxf(v, 0.0f);
    }
    *reinterpret_cast<float4*>(
      &xout[((size_t)(b*CMID + ocb + (g<<2) + q) << 12) + ((ty0+py) << 6) + tx0 + 4]) = ov2;
  }
}

// ---------------- 1x1 convs: 512 -> 24 (cls) + 48 (bbox) ----------------
__global__ __launch_bounds__(256) void conv1x1K(
    const float* __restrict__ x,
    const float* __restrict__ Ws, const float* __restrict__ bs,
    const float* __restrict__ Wb, const float* __restrict__ bb,
    float* __restrict__ clsRaw, float* __restrict__ bboxRaw){
  __shared__ float wLds[32*72];
  const int tid = threadIdx.x;
  const int px = tid & 63;
  const int og = tid >> 6;
  const int px0 = (blockIdx.x & 63) << 6;
  const int b = blockIdx.x >> 6;
  double m[18];
  float cc[18];
#pragma unroll
  for (int j=0;j<18;j++){ m[j]=0.0; cc[j]=0.0f; }
  for (int cb=0; cb<CMID; cb+=32){
#pragma unroll
    for (int i=0;i<9;i++){
      int lin = tid + i*256;                 // 2304 weights
      int c = lin / 72;
      int j = lin - c*72;
      wLds[lin] = (j < 24) ? Ws[(size_t)j*512 + cb + c]
                           : Wb[(size_t)(j-24)*512 + cb + c];
    }
    __syncthreads();
    for (int c=0;c<32;c++){
      float xv = x[((size_t)(b*CMID + cb + c) << 12) + px0 + px];
      const float* wp = &wLds[c*72 + og*18];
#pragma unroll
      for (int j=0;j<18;j++) cc[j] = fmaf(wp[j], xv, cc[j]);
    }
#pragma unroll
    for (int j=0;j<18;j++){ m[j] += (double)cc[j]; cc[j]=0.0f; }
    __syncthreads();
  }
#pragma unroll
  for (int j=0;j<18;j++){
    int jg = og*18 + j;
    float bias = (jg < 24) ? bs[jg] : bb[jg-24];
    float v = __fadd_rn((float)m[j], bias);
    if (jg < 24) clsRaw[((size_t)(b*24 + jg) << 12) + px0 + px] = v;
    else         bboxRaw[((size_t)(b*48 + jg - 24) << 12) + px0 + px] = v;
  }
}

// ---------------- decode + clip + min-size + score bits + hi-histogram ----------------
__global__ void decodeK(const float* __restrict__ clsRaw,
                        const float* __restrict__ bboxRaw,
                        const float* __restrict__ imInfo,
                        float* __restrict__ boxes, uint32_t* __restrict__ ubits,
                        uint32_t* __restrict__ hist1){
  int n = blockIdx.x*256 + threadIdx.x;
  if (n >= NBATCH*NANCH) return;
  int b = n / NANCH;
  int r = n - b*NANCH;
  int px = r / 12;
  int a = r - px*12;
  int yi = px >> 6, xi = px & 63;
  const int w0t[3] = {23,16,11};
  const int h0t[3] = {12,16,22};
  int ridx = a >> 2;
  int sh = 2 + (a & 3);                    // scale 4<<(a&3)
  float W = (float)(w0t[ridx] << sh);      // exact anchor width
  float H = (float)(h0t[ridx] << sh);
  float cx = (float)((xi << 4) + 8);       // exact anchor center
  float cy = (float)((yi << 4) + 8);

  size_t cbase = ((size_t)b*24 << 12) + px;
  float sc0 = clsRaw[cbase + ((size_t)a       << 12)];   // bg
  float sc1 = clsRaw[cbase + ((size_t)(12+a)  << 12)];   // fg
  size_t bbase = ((size_t)b*48 << 12) + px;
  float dx = bboxRaw[bbase + ((size_t)(4*a+0) << 12)];
  float dy = bboxRaw[bbase + ((size_t)(4*a+1) << 12)];
  float dw = bboxRaw[bbase + ((size_t)(4*a+2) << 12)];
  float dh = bboxRaw[bbase + ((size_t)(4*a+3) << 12)];

  float imh = imInfo[b*3+0], imw = imInfo[b*3+1], iscale = imInfo[b*3+2];

  float pcx = __fadd_rn(__fmul_rn(dx, W), cx);
  float pcy = __fadd_rn(__fmul_rn(dy, H), cy);
  float pw  = __fmul_rn(expf(dw), W);
  float ph  = __fmul_rn(expf(dh), H);
  float hw = __fmul_rn(0.5f, pw), hh = __fmul_rn(0.5f, ph);
  float x1 = __fsub_rn(pcx, hw), x2 = __fadd_rn(pcx, hw);
  float y1 = __fsub_rn(pcy, hh), y2 = __fadd_rn(pcy, hh);
  float xmax = __fsub_rn(imw, 1.0f), ymax = __fsub_rn(imh, 1.0f);
  x1 = fminf(fmaxf(x1, 0.0f), xmax);
  y1 = fminf(fmaxf(y1, 0.0f), ymax);
  x2 = fminf(fmaxf(x2, 0.0f), xmax);
  y2 = fminf(fmaxf(y2, 0.0f), ymax);
  float ms = __fmul_rn(16.0f, iscale);
  bool valid = (__fadd_rn(__fsub_rn(x2,x1),1.0f) >= ms) &&
               (__fadd_rn(__fsub_rn(y2,y1),1.0f) >= ms);

  float mm = fmaxf(sc0, sc1);
  float e0 = expf(__fsub_rn(sc0, mm));
  float e1 = expf(__fsub_rn(sc1, mm));
  float s  = __fdiv_rn(e1, __fadd_rn(e0, e1));

  uint32_t u = __float_as_uint(s);
  u = (u & 0x80000000u) ? ~u : (u | 0x80000000u);
  if (!valid) u = 0x007FFFFFu;             // transform(-inf)

  float4 bx = make_float4(x1, y1, x2, y2);
  *reinterpret_cast<float4*>(&boxes[(size_t)n*4]) = bx;
  ubits[n] = u;
  atomicAdd(&hist1[((size_t)b << 16) + (u >> 16)], 1u);
}

__global__ void histLoK(const uint32_t* __restrict__ ubits,
                        const uint32_t* __restrict__ thrWS, uint32_t* __restrict__ hist2){
  int n = blockIdx.x*256 + threadIdx.x;
  if (n >= NBATCH*NANCH) return;
  int b = n / NANCH;
  uint32_t u = ubits[n];
  if ((u >> 16) == thrWS[b*4+0])
    atomicAdd(&hist2[((size_t)b << 16) + (u & 0xFFFFu)], 1u);
}

// find bin B with count(>B)+base < 6000 <= count(>=B)+base
__global__ __launch_bounds__(1024) void selectK(const uint32_t* __restrict__ hist,
                                                uint32_t* __restrict__ thrWS, int stage){
  __shared__ uint32_t sA[1024];
  const int b = blockIdx.x;
  const uint32_t* h = hist + ((size_t)b << 16);
  const int tid = threadIdx.x;
  uint32_t base = (stage == 0) ? 0u : thrWS[b*4+1];
  uint32_t seg = 0;
  int b0 = tid << 6;
  for (int k=0;k<64;k++) seg += h[b0+k];
  sA[tid] = seg;
  __syncthreads();
  for (int off=1; off<1024; off<<=1){
    uint32_t v = (tid+off < 1024) ? sA[tid+off] : 0u;
    __syncthreads();
    sA[tid] += v;
    __syncthreads();
  }
  uint32_t inc = sA[tid];          // count(bins >= b0)
  uint32_t above = inc - seg;      // count(bins >  segment top)
  if (base + above < 6000u && base + inc >= 6000u){
    uint32_t c = base + above;
    for (int bin = b0+63; bin >= b0; bin--){
      uint32_t hh = h[bin];
      if (c + hh >= 6000u){
        if (stage == 0){ thrWS[b*4+0] = (uint32_t)bin; thrWS[b*4+1] = c; }
        else { thrWS[b*4+2] = (thrWS[b*4+0] << 16) | (uint32_t)bin; thrWS[b*4+3] = c; }
        break;
      }
      c += hh;
    }
  }
}

// ---------------- compact candidates at/above threshold ----------------
__global__ void compactK(const uint32_t* __restrict__ ubits,
                         const uint32_t* __restrict__ thrWS,
                         uint32_t* __restrict__ cnts,
                         uint64_t* __restrict__ keyHi, uint64_t* __restrict__ keyEq){
  int n = blockIdx.x*256 + threadIdx.x;
  if (n >= NBATCH*NANCH) return;
  int b = n / NANCH;
  int r = n - b*NANCH;
  uint32_t u = ubits[n];
  uint32_t us = thrWS[b*4+2];
  if (u < us) return;
  uint64_t key = ((uint64_t)(~u) << 32) | (uint32_t)r;  // asc = score desc, idx asc
  if (u > us){
    uint32_t p = atomicAdd(&cnts[b*2+0], 1u);
    if (p < 8192u) keyHi[((size_t)b << 13) + p] = key;
  } else {
    uint32_t p = atomicAdd(&cnts[b*2+1], 1u);
    if (p < 8192u) keyEq[((size_t)b << 13) + p] = key;
  }
}

// ---------------- bitonic sort 8192 + gather ranked boxes ----------------
__global__ __launch_bounds__(1024) void sortGatherK(
    const uint64_t* __restrict__ keyHi, const uint64_t* __restrict__ keyEq,
    const uint32_t* __restrict__ cnts, const float* __restrict__ boxes,
    float* __restrict__ rbox){
  __shared__ uint64_t keys[8192];
  const int b = blockIdx.x;
  const int tid = threadIdx.x;
  uint32_t nHi = cnts[b*2+0];
  if (nHi > 8192u) nHi = 8192u;
  uint32_t nEq = cnts[b*2+1];
  if (nEq > 8192u - nHi) nEq = 8192u - nHi;
  for (int i=tid; i<8192; i+=1024){
    uint64_t k;
    if (i < (int)nHi) k = keyHi[((size_t)b << 13) + i];
    else if (i < (int)(nHi + nEq)) k = keyEq[((size_t)b << 13) + (i - nHi)];
    else k = ~0ULL;
    keys[i] = k;
  }
  __syncthreads();
  for (unsigned kk = 2; kk <= 8192; kk <<= 1){
    for (unsigned j = kk >> 1; j > 0; j >>= 1){
      for (unsigned i = tid; i < 8192; i += 1024){
        unsigned l = i ^ j;
        if (l > i){
          bool up = ((i & kk) == 0);
          uint64_t a = keys[i], c = keys[l];
          if ((a > c) == up){ keys[i] = c; keys[l] = a; }
        }
      }
      __syncthreads();
    }
  }
  for (int r = tid; r < PRE_NMS_N; r += 1024){
    uint32_t idx = (uint32_t)(keys[r] & 0xFFFFFFFFu);
    float4 v = *reinterpret_cast<const float4*>(&boxes[((size_t)b*NANCH + idx)*4]);
    *reinterpret_cast<float4*>(&rbox[((size_t)b*PRE_NMS_N + r)*4]) = v;
  }
}

// ---------------- NMS: pairwise suppression bit-matrix ----------------
__global__ __launch_bounds__(64) void nmsMaskK(const float* __restrict__ rbox,
                                               uint64_t* __restrict__ mask){
  const int b = blockIdx.z;
  const int ib = blockIdx.y;
  const int jb = blockIdx.x;
  const int lane = threadIdx.x;
  uint64_t* mrow = &mask[(size_t)b*PRE_NMS_N*96];
  if (jb < ib){                       // all jg<ig here: words are zero by construction
    int ig = (ib << 6) + lane;
    if (ig < PRE_NMS_N) mrow[(size_t)ig*96 + jb] = 0ull;
    return;
  }
  __shared__ float rb[64][4];
  const int ig0 = ib << 6;
  {
    int ig = ig0 + lane;
    float4 v = make_float4(0.f,0.f,0.f,0.f);
    if (ig < PRE_NMS_N) v = *reinterpret_cast<const float4*>(&rbox[((size_t)b*PRE_NMS_N + ig)*4]);
    rb[lane][0]=v.x; rb[lane][1]=v.y; rb[lane][2]=v.z; rb[lane][3]=v.w;
  }
  const int jg = (jb << 6) + lane;
  const bool jok = jg < PRE_NMS_N;
  float4 cb = make_float4(0.f,0.f,0.f,0.f);
  if (jok) cb = *reinterpret_cast<const float4*>(&rbox[((size_t)b*PRE_NMS_N + jg)*4]);
  float areaJ = __fmul_rn(__fadd_rn(__fsub_rn(cb.z,cb.x),1.0f),
                          __fadd_rn(__fsub_rn(cb.w,cb.y),1.0f));
  __syncthreads();
#pragma unroll 4
  for (int i=0;i<64;i++){
    int ig = ig0 + i;
    if (ig >= PRE_NMS_N) break;
    float x1=rb[i][0], y1=rb[i][1], x2=rb[i][2], y2=rb[i][3];
    float areaI = __fmul_rn(__fadd_rn(__fsub_rn(x2,x1),1.0f),
                            __fadd_rn(__fsub_rn(y2,y1),1.0f));
    float xx1 = fmaxf(x1, cb.x);
    float yy1 = fmaxf(y1, cb.y);
    float xx2 = fminf(x2, cb.z);
    float yy2 = fminf(y2, cb.w);
    float ww = fmaxf(__fadd_rn(__fsub_rn(xx2,xx1),1.0f), 0.0f);
    float hh = fmaxf(__fadd_rn(__fsub_rn(yy2,yy1),1.0f), 0.0f);
    float inter = __fmul_rn(ww,hh);
    float iou = __fdiv_rn(inter, __fsub_rn(__fadd_rn(areaI, areaJ), inter));
    bool bit = jok && (jg > ig) && (iou > 0.7f);
    uint64_t wword = __ballot(bit);
    if (lane == 0) mrow[(size_t)ig*96 + jb] = wword;
  }
}

// ---------------- NMS: single-wave greedy scan over bit-matrix ----------------
__global__ __launch_bounds__(64) void nmsScanK(const float* __restrict__ rbox,
                                               const uint64_t* __restrict__ mask,
                                               float* __restrict__ out){
  const int b = blockIdx.x;
  const int lane = threadIdx.x;
  const uint64_t* mrow = &mask[(size_t)b*PRE_NMS_N*96];
  uint64_t s0 = 0ull, s1 = 0ull;
  int cnt = 0;
  for (int i=0; i<PRE_NMS_N; i++){
    int w = i >> 6;
    uint64_t sw = (w < 64) ? __shfl(s0, w) : __shfl(s1, w-64);
    if (!((sw >> (i & 63)) & 1ull)){
      if (lane == 0){
        const float* s = &rbox[((size_t)b*PRE_NMS_N + i)*4];
        float* o = &out[(size_t)(b*POST_NMS_N + cnt)*5];
        o[0] = (float)b; o[1]=s[0]; o[2]=s[1]; o[3]=s[2]; o[4]=s[3];
      }
      cnt++;
      if (cnt == POST_NMS_N) break;
      const uint64_t* mr = mrow + (size_t)i*96;
      s0 |= mr[lane];
      if (lane < 30) s1 |= mr[64+lane];
    }
  }
  for (int r = cnt + lane; r < POST_NMS_N; r += 64){
    float* o = &out[(size_t)(b*POST_NMS_N + r)*5];
    o[0] = (float)b; o[1]=0.f; o[2]=0.f; o[3]=0.f; o[4]=0.f;
  }
}

extern "C" void kernel_launch(void* const* d_in, const int* in_sizes, int n_in,
                              void* d_out, int out_size, void* d_ws, size_t ws_size,
                              hipStream_t stream) {
  const float* features = (const float*)d_in[0];
  const float* im_info  = (const float*)d_in[1];
  const float* W1 = (const float*)d_in[2];
  const float* b1 = (const float*)d_in[3];
  const float* Ws = (const float*)d_in[4];
  const float* bs = (const float*)d_in[5];
  const float* Wb = (const float*)d_in[6];
  const float* bb = (const float*)d_in[7];
  float* out = (float*)d_out;
  char* ws = (char*)d_ws;

  const size_t offX     = 0;                          // x (4,512,4096) — reused as NMS mask later
  const size_t offCls   = offX     + (size_t)4*512*4096*4;
  const size_t offBbox  = offCls   + (size_t)4*24*4096*4;
  const size_t offBoxes = offBbox  + (size_t)4*48*4096*4;
  const size_t offU     = offBoxes + (size_t)4*49152*4*4;
  const size_t offH1    = offU     + (size_t)4*49152*4;
  const size_t offH2    = offH1    + (size_t)4*65536*4;
  const size_t offCtr   = offH2    + (size_t)4*65536*4;
  const size_t offKHi   = offCtr   + 256;
  const size_t offKEq   = offKHi   + (size_t)4*8192*8;
  const size_t offRbox  = offKEq   + (size_t)4*8192*8;

  float*    x       = (float*)(ws + offX);
  float*    clsRaw  = (float*)(ws + offCls);
  float*    bboxRaw = (float*)(ws + offBbox);
  float*    boxes   = (float*)(ws + offBoxes);
  uint32_t* ubits   = (uint32_t*)(ws + offU);
  uint32_t* hist1   = (uint32_t*)(ws + offH1);
  uint32_t* hist2   = (uint32_t*)(ws + offH2);
  uint32_t* thrWS   = (uint32_t*)(ws + offCtr);       // 16 u32
  uint32_t* cnts    = thrWS + 16;                     // 8 u32
  uint64_t* keyHi   = (uint64_t*)(ws + offKHi);
  uint64_t* keyEq   = (uint64_t*)(ws + offKEq);
  float*    rbox    = (float*)(ws + offRbox);
  uint64_t* mask    = (uint64_t*)(ws + offX);         // aliases x (dead after conv1x1)

  // zero hist1+hist2+counters (contiguous region)
  {
    int nWords = (int)(((offCtr + 256) - offH1) / 4);
    int grid = (nWords + 255) / 256;
    zeroK<<<grid, 256, 0, stream>>>((uint32_t*)(ws + offH1), nWords);
  }
  conv3x3K<<<dim3(64, 4, 4), 256, 0, stream>>>(features, W1, b1, x);
  conv1x1K<<<256, 256, 0, stream>>>(x, Ws, bs, Wb, bb, clsRaw, bboxRaw);
  {
    int grid = (NBATCH*NANCH + 255) / 256;   // 768
    decodeK<<<grid, 256, 0, stream>>>(clsRaw, bboxRaw, im_info, boxes, ubits, hist1);
    selectK<<<4, 1024, 0, stream>>>(hist1, thrWS, 0);
    histLoK<<<grid, 256, 0, stream>>>(ubits, thrWS, hist2);
    selectK<<<4, 1024, 0, stream>>>(hist2, thrWS, 1);
    compactK<<<grid, 256, 0, stream>>>(ubits, thrWS, cnts, keyHi, keyEq);
  }
  sortGatherK<<<4, 1024, 0, stream>>>(keyHi, keyEq, cnts, boxes, rbox);
  nmsMaskK<<<dim3(94, 94, 4), 64, 0, stream>>>(rbox, mask);
  nmsScanK<<<4, 64, 0, stream>>>(rbox, mask, out);
}

// Round 16
// 2413.592 us; speedup vs baseline: 1.5796x; 1.5796x over previous
//
#include <hip/hip_runtime.h>
#include <stdint.h>

#define CIN 768
#define CMID 512
#define NPIX 4096
#define NANCH 49152
#define NBATCH 4
#define PRE_NMS_N 6000
#define POST_NMS_N 300

// ---------------- zero scratch (hist + counters) ----------------
__global__ void zeroK(uint32_t* __restrict__ p, int nWords){
  int i = blockIdx.x * 256 + threadIdx.x;
  if (i < nWords) p[i] = 0u;
}

// ---------------- conv 3x3, 768->512, bias, relu ----------------
// CHAMPION CONFIG (r8, measured 1780us, total 2414us, absmax 0.0).
// 256 thr = 32 oc-quads x 8 rows; thread computes 4 oc x 8 px.
// Weight LDS [ic][ky][g][q*3+kx]: per (ic,ky) 12 contiguous floats = 3
// aligned b128 (8 unique addrs/wave -> all 32 banks once, conflict-free).
// fp64 masters, fp32 cacc drained every 4 global ic, per-output fma order
// (ic asc, ky asc, kx asc) — the max-margin numerics (r13: ~1e-6 reorder
// flips a selection; fp64 masters are ~1e-8 from reference).
// LDS padded to 43520 B -> 3 blocks/CU -> LLVM reg budget ~168, allocates
// 128, no spill. 8-round ledger: every perturbation (prefetch r6, fp32+
// pingpong r10, LDS 40960 r11, 16px r12/r14, half-chunk r15) regresses —
// this is the structure's plateau (~1.36x the 920us LDS-demand floor).
__global__ __launch_bounds__(256) void conv3x3K(
    const float* __restrict__ feat, const float* __restrict__ W1,
    const float* __restrict__ b1, float* __restrict__ xout){
  __shared__ float wLds[9920];   // 9216 used: [ic 0..7][ky 0..2][g 0..31][q*3+kx]
  __shared__ float fLds[960];    // [ic][row 0..9][12], col c <-> x = tx0+c-1
  const int tid = threadIdx.x;
  const int g  = tid >> 3;       // oc-quad 0..31
  const int py = tid & 7;        // output row 0..7
  const int ty0 = (blockIdx.x >> 3) << 3;
  const int tx0 = (blockIdx.x & 7) << 3;
  const int ocb = blockIdx.y << 7;   // 128 oc per block
  const int b = blockIdx.z;

  // ---- weight staging consts: thread stages 36 contiguous floats ----
  const int oc_t  = tid >> 1;        // 0..127
  const int halfw = tid & 1;         // ic_local 0..3 or 4..7
  const float* wsrc0 = W1 + (size_t)(ocb + oc_t)*6912 + halfw*36;
  const int gq   = (oc_t>>2)*12 + (oc_t&3)*3;   // g*12 + q*3
  const int icl0 = halfw << 2;                  // ic_local base

  // ---- feature staging consts ----
  int fdst[4]; int fsrc[4]; bool fgo[4]; bool fact[4];
#pragma unroll
  for (int i=0;i<4;i++){
    int lin = tid + (i<<8);
    fact[i] = lin < 800;
    int l2 = fact[i] ? lin : 0;
    int ic = l2/100; int r2 = l2 - ic*100;
    int row = r2/10; int col = r2 - row*10;
    int gy = ty0 + row - 1, gx = tx0 + col - 1;
    fgo[i]  = fact[i] && gy>=0 && gy<64 && gx>=0 && gx<64;
    fdst[i] = ic*120 + row*12 + col;
    fsrc[i] = (ic<<12) + (gy<<6) + gx;
  }
  const float* fbase = feat + ((size_t)(b*CIN) << 12);

  double macc[4][8];
  float cacc[4][8];
#pragma unroll
  for (int q=0;q<4;q++)
#pragma unroll
    for (int j=0;j<8;j++){ macc[q][j]=0.0; cacc[q][j]=0.0f; }

  for (int icb = 0; icb < CIN; icb += 8){
    // ---- stage weights: 36 contiguous src floats -> [ic][ky][g][q*3+kx] ----
    {
      const float* s = wsrc0 + (size_t)icb*9;
      float w0[36];
#pragma unroll
      for (int m=0;m<9;m++){
        float4 v = *reinterpret_cast<const float4*>(s + (m<<2));
        w0[4*m+0]=v.x; w0[4*m+1]=v.y; w0[4*m+2]=v.z; w0[4*m+3]=v.w;
      }
#pragma unroll
      for (int r=0;r<4;r++)
#pragma unroll
        for (int k=0;k<9;k++)
          wLds[(icl0+r)*1152 + (k/3)*384 + gq + (k%3)] = w0[r*9+k];
    }
    // ---- stage features: 8 ic x 10 rows x 10 cols ----
#pragma unroll
    for (int i=0;i<4;i++){
      if (fact[i]){
        float v = 0.0f;
        if (fgo[i]) v = fbase[((size_t)icb << 12) + fsrc[i]];
        fLds[fdst[i]] = v;
      }
    }
    __syncthreads();
    // ---- compute 8 ic ----
#pragma unroll
    for (int ic=0; ic<8; ic++){
      const float* fb = &fLds[ic*120 + py*12];
      const float* wb = &wLds[ic*1152 + g*12];
#pragma unroll
      for (int ky=0;ky<3;ky++){
        float4 a = *reinterpret_cast<const float4*>(fb + ky*12);
        float4 c = *reinterpret_cast<const float4*>(fb + ky*12 + 4);
        float2 e = *reinterpret_cast<const float2*>(fb + ky*12 + 8);
        const float f[10] = {a.x,a.y,a.z,a.w,c.x,c.y,c.z,c.w,e.x,e.y};
        const float* wp = wb + ky*384;
        float4 wa = *reinterpret_cast<const float4*>(wp);
        float4 wv = *reinterpret_cast<const float4*>(wp+4);
        float4 wc = *reinterpret_cast<const float4*>(wp+8);
        const float w12[12] = {wa.x,wa.y,wa.z,wa.w, wv.x,wv.y,wv.z,wv.w,
                               wc.x,wc.y,wc.z,wc.w};
#pragma unroll
        for (int q=0;q<4;q++)
#pragma unroll
          for (int kx=0;kx<3;kx++){
            float we = w12[q*3+kx];
#pragma unroll
            for (int j=0;j<8;j++)
              cacc[q][j] = fmaf(we, f[j+kx], cacc[q][j]);
          }
      }
      if ((ic & 3) == 3){
#pragma unroll
        for (int q=0;q<4;q++)
#pragma unroll
          for (int j=0;j<8;j++){ macc[q][j] += (double)cacc[q][j]; cacc[q][j]=0.0f; }
      }
    }
    __syncthreads();
  }
#pragma unroll
  for (int q=0;q<4;q++){
    float bias = b1[ocb + (g<<2) + q];
    float4 o0, o1;
    float* p0 = (float*)&o0; float* p1 = (float*)&o1;
#pragma unroll
    for (int j=0;j<4;j++){
      p0[j] = fmaxf(__fadd_rn((float)macc[q][j],   bias), 0.0f);
      p1[j] = fmaxf(__fadd_rn((float)macc[q][j+4], bias), 0.0f);
    }
    size_t base = ((size_t)(b*CMID + ocb + (g<<2) + q) << 12) + ((ty0+py) << 6) + tx0;
    *reinterpret_cast<float4*>(&xout[base])     = o0;
    *reinterpret_cast<float4*>(&xout[base + 4]) = o1;
  }
}

// ---------------- 1x1 convs: 512 -> 24 (cls) + 48 (bbox) ----------------
__global__ __launch_bounds__(256) void conv1x1K(
    const float* __restrict__ x,
    const float* __restrict__ Ws, const float* __restrict__ bs,
    const float* __restrict__ Wb, const float* __restrict__ bb,
    float* __restrict__ clsRaw, float* __restrict__ bboxRaw){
  __shared__ float wLds[32*72];
  const int tid = threadIdx.x;
  const int px = tid & 63;
  const int og = tid >> 6;
  const int px0 = (blockIdx.x & 63) << 6;
  const int b = blockIdx.x >> 6;
  double m[18];
  float cc[18];
#pragma unroll
  for (int j=0;j<18;j++){ m[j]=0.0; cc[j]=0.0f; }
  for (int cb=0; cb<CMID; cb+=32){
#pragma unroll
    for (int i=0;i<9;i++){
      int lin = tid + i*256;                 // 2304 weights
      int c = lin / 72;
      int j = lin - c*72;
      wLds[lin] = (j < 24) ? Ws[(size_t)j*512 + cb + c]
                           : Wb[(size_t)(j-24)*512 + cb + c];
    }
    __syncthreads();
    for (int c=0;c<32;c++){
      float xv = x[((size_t)(b*CMID + cb + c) << 12) + px0 + px];
      const float* wp = &wLds[c*72 + og*18];
#pragma unroll
      for (int j=0;j<18;j++) cc[j] = fmaf(wp[j], xv, cc[j]);
    }
#pragma unroll
    for (int j=0;j<18;j++){ m[j] += (double)cc[j]; cc[j]=0.0f; }
    __syncthreads();
  }
#pragma unroll
  for (int j=0;j<18;j++){
    int jg = og*18 + j;
    float bias = (jg < 24) ? bs[jg] : bb[jg-24];
    float v = __fadd_rn((float)m[j], bias);
    if (jg < 24) clsRaw[((size_t)(b*24 + jg) << 12) + px0 + px] = v;
    else         bboxRaw[((size_t)(b*48 + jg - 24) << 12) + px0 + px] = v;
  }
}

// ---------------- decode + clip + min-size + score bits + hi-histogram ----------------
__global__ void decodeK(const float* __restrict__ clsRaw,
                        const float* __restrict__ bboxRaw,
                        const float* __restrict__ imInfo,
                        float* __restrict__ boxes, uint32_t* __restrict__ ubits,
                        uint32_t* __restrict__ hist1){
  int n = blockIdx.x*256 + threadIdx.x;
  if (n >= NBATCH*NANCH) return;
  int b = n / NANCH;
  int r = n - b*NANCH;
  int px = r / 12;
  int a = r - px*12;
  int yi = px >> 6, xi = px & 63;
  const int w0t[3] = {23,16,11};
  const int h0t[3] = {12,16,22};
  int ridx = a >> 2;
  int sh = 2 + (a & 3);                    // scale 4<<(a&3)
  float W = (float)(w0t[ridx] << sh);      // exact anchor width
  float H = (float)(h0t[ridx] << sh);
  float cx = (float)((xi << 4) + 8);       // exact anchor center
  float cy = (float)((yi << 4) + 8);

  size_t cbase = ((size_t)b*24 << 12) + px;
  float sc0 = clsRaw[cbase + ((size_t)a       << 12)];   // bg
  float sc1 = clsRaw[cbase + ((size_t)(12+a)  << 12)];   // fg
  size_t bbase = ((size_t)b*48 << 12) + px;
  float dx = bboxRaw[bbase + ((size_t)(4*a+0) << 12)];
  float dy = bboxRaw[bbase + ((size_t)(4*a+1) << 12)];
  float dw = bboxRaw[bbase + ((size_t)(4*a+2) << 12)];
  float dh = bboxRaw[bbase + ((size_t)(4*a+3) << 12)];

  float imh = imInfo[b*3+0], imw = imInfo[b*3+1], iscale = imInfo[b*3+2];

  float pcx = __fadd_rn(__fmul_rn(dx, W), cx);
  float pcy = __fadd_rn(__fmul_rn(dy, H), cy);
  float pw  = __fmul_rn(expf(dw), W);
  float ph  = __fmul_rn(expf(dh), H);
  float hw = __fmul_rn(0.5f, pw), hh = __fmul_rn(0.5f, ph);
  float x1 = __fsub_rn(pcx, hw), x2 = __fadd_rn(pcx, hw);
  float y1 = __fsub_rn(pcy, hh), y2 = __fadd_rn(pcy, hh);
  float xmax = __fsub_rn(imw, 1.0f), ymax = __fsub_rn(imh, 1.0f);
  x1 = fminf(fmaxf(x1, 0.0f), xmax);
  y1 = fminf(fmaxf(y1, 0.0f), ymax);
  x2 = fminf(fmaxf(x2, 0.0f), xmax);
  y2 = fminf(fmaxf(y2, 0.0f), ymax);
  float ms = __fmul_rn(16.0f, iscale);
  bool valid = (__fadd_rn(__fsub_rn(x2,x1),1.0f) >= ms) &&
               (__fadd_rn(__fsub_rn(y2,y1),1.0f) >= ms);

  float mm = fmaxf(sc0, sc1);
  float e0 = expf(__fsub_rn(sc0, mm));
  float e1 = expf(__fsub_rn(sc1, mm));
  float s  = __fdiv_rn(e1, __fadd_rn(e0, e1));

  uint32_t u = __float_as_uint(s);
  u = (u & 0x80000000u) ? ~u : (u | 0x80000000u);
  if (!valid) u = 0x007FFFFFu;             // transform(-inf)

  float4 bx = make_float4(x1, y1, x2, y2);
  *reinterpret_cast<float4*>(&boxes[(size_t)n*4]) = bx;
  ubits[n] = u;
  atomicAdd(&hist1[((size_t)b << 16) + (u >> 16)], 1u);
}

__global__ void histLoK(const uint32_t* __restrict__ ubits,
                        const uint32_t* __restrict__ thrWS, uint32_t* __restrict__ hist2){
  int n = blockIdx.x*256 + threadIdx.x;
  if (n >= NBATCH*NANCH) return;
  int b = n / NANCH;
  uint32_t u = ubits[n];
  if ((u >> 16) == thrWS[b*4+0])
    atomicAdd(&hist2[((size_t)b << 16) + (u & 0xFFFFu)], 1u);
}

// find bin B with count(>B)+base < 6000 <= count(>=B)+base
__global__ __launch_bounds__(1024) void selectK(const uint32_t* __restrict__ hist,
                                                uint32_t* __restrict__ thrWS, int stage){
  __shared__ uint32_t sA[1024];
  const int b = blockIdx.x;
  const uint32_t* h = hist + ((size_t)b << 16);
  const int tid = threadIdx.x;
  uint32_t base = (stage == 0) ? 0u : thrWS[b*4+1];
  uint32_t seg = 0;
  int b0 = tid << 6;
  for (int k=0;k<64;k++) seg += h[b0+k];
  sA[tid] = seg;
  __syncthreads();
  for (int off=1; off<1024; off<<=1){
    uint32_t v = (tid+off < 1024) ? sA[tid+off] : 0u;
    __syncthreads();
    sA[tid] += v;
    __syncthreads();
  }
  uint32_t inc = sA[tid];          // count(bins >= b0)
  uint32_t above = inc - seg;      // count(bins >  segment top)
  if (base + above < 6000u && base + inc >= 6000u){
    uint32_t c = base + above;
    for (int bin = b0+63; bin >= b0; bin--){
      uint32_t hh = h[bin];
      if (c + hh >= 6000u){
        if (stage == 0){ thrWS[b*4+0] = (uint32_t)bin; thrWS[b*4+1] = c; }
        else { thrWS[b*4+2] = (thrWS[b*4+0] << 16) | (uint32_t)bin; thrWS[b*4+3] = c; }
        break;
      }
      c += hh;
    }
  }
}

// ---------------- compact candidates at/above threshold ----------------
__global__ void compactK(const uint32_t* __restrict__ ubits,
                         const uint32_t* __restrict__ thrWS,
                         uint32_t* __restrict__ cnts,
                         uint64_t* __restrict__ keyHi, uint64_t* __restrict__ keyEq){
  int n = blockIdx.x*256 + threadIdx.x;
  if (n >= NBATCH*NANCH) return;
  int b = n / NANCH;
  int r = n - b*NANCH;
  uint32_t u = ubits[n];
  uint32_t us = thrWS[b*4+2];
  if (u < us) return;
  uint64_t key = ((uint64_t)(~u) << 32) | (uint32_t)r;  // asc = score desc, idx asc
  if (u > us){
    uint32_t p = atomicAdd(&cnts[b*2+0], 1u);
    if (p < 8192u) keyHi[((size_t)b << 13) + p] = key;
  } else {
    uint32_t p = atomicAdd(&cnts[b*2+1], 1u);
    if (p < 8192u) keyEq[((size_t)b << 13) + p] = key;
  }
}

// ---------------- bitonic sort 8192 + gather ranked boxes ----------------
__global__ __launch_bounds__(1024) void sortGatherK(
    const uint64_t* __restrict__ keyHi, const uint64_t* __restrict__ keyEq,
    const uint32_t* __restrict__ cnts, const float* __restrict__ boxes,
    float* __restrict__ rbox){
  __shared__ uint64_t keys[8192];
  const int b = blockIdx.x;
  const int tid = threadIdx.x;
  uint32_t nHi = cnts[b*2+0];
  if (nHi > 8192u) nHi = 8192u;
  uint32_t nEq = cnts[b*2+1];
  if (nEq > 8192u - nHi) nEq = 8192u - nHi;
  for (int i=tid; i<8192; i+=1024){
    uint64_t k;
    if (i < (int)nHi) k = keyHi[((size_t)b << 13) + i];
    else if (i < (int)(nHi + nEq)) k = keyEq[((size_t)b << 13) + (i - nHi)];
    else k = ~0ULL;
    keys[i] = k;
  }
  __syncthreads();
  for (unsigned kk = 2; kk <= 8192; kk <<= 1){
    for (unsigned j = kk >> 1; j > 0; j >>= 1){
      for (unsigned i = tid; i < 8192; i += 1024){
        unsigned l = i ^ j;
        if (l > i){
          bool up = ((i & kk) == 0);
          uint64_t a = keys[i], c = keys[l];
          if ((a > c) == up){ keys[i] = c; keys[l] = a; }
        }
      }
      __syncthreads();
    }
  }
  for (int r = tid; r < PRE_NMS_N; r += 1024){
    uint32_t idx = (uint32_t)(keys[r] & 0xFFFFFFFFu);
    float4 v = *reinterpret_cast<const float4*>(&boxes[((size_t)b*NANCH + idx)*4]);
    *reinterpret_cast<float4*>(&rbox[((size_t)b*PRE_NMS_N + r)*4]) = v;
  }
}

// ---------------- NMS: pairwise suppression bit-matrix ----------------
__global__ __launch_bounds__(64) void nmsMaskK(const float* __restrict__ rbox,
                                               uint64_t* __restrict__ mask){
  const int b = blockIdx.z;
  const int ib = blockIdx.y;
  const int jb = blockIdx.x;
  const int lane = threadIdx.x;
  uint64_t* mrow = &mask[(size_t)b*PRE_NMS_N*96];
  if (jb < ib){                       // all jg<ig here: words are zero by construction
    int ig = (ib << 6) + lane;
    if (ig < PRE_NMS_N) mrow[(size_t)ig*96 + jb] = 0ull;
    return;
  }
  __shared__ float rb[64][4];
  const int ig0 = ib << 6;
  {
    int ig = ig0 + lane;
    float4 v = make_float4(0.f,0.f,0.f,0.f);
    if (ig < PRE_NMS_N) v = *reinterpret_cast<const float4*>(&rbox[((size_t)b*PRE_NMS_N + ig)*4]);
    rb[lane][0]=v.x; rb[lane][1]=v.y; rb[lane][2]=v.z; rb[lane][3]=v.w;
  }
  const int jg = (jb << 6) + lane;
  const bool jok = jg < PRE_NMS_N;
  float4 cb = make_float4(0.f,0.f,0.f,0.f);
  if (jok) cb = *reinterpret_cast<const float4*>(&rbox[((size_t)b*PRE_NMS_N + jg)*4]);
  float areaJ = __fmul_rn(__fadd_rn(__fsub_rn(cb.z,cb.x),1.0f),
                          __fadd_rn(__fsub_rn(cb.w,cb.y),1.0f));
  __syncthreads();
#pragma unroll 4
  for (int i=0;i<64;i++){
    int ig = ig0 + i;
    if (ig >= PRE_NMS_N) break;
    float x1=rb[i][0], y1=rb[i][1], x2=rb[i][2], y2=rb[i][3];
    float areaI = __fmul_rn(__fadd_rn(__fsub_rn(x2,x1),1.0f),
                            __fadd_rn(__fsub_rn(y2,y1),1.0f));
    float xx1 = fmaxf(x1, cb.x);
    float yy1 = fmaxf(y1, cb.y);
    float xx2 = fminf(x2, cb.z);
    float yy2 = fminf(y2, cb.w);
    float ww = fmaxf(__fadd_rn(__fsub_rn(xx2,xx1),1.0f), 0.0f);
    float hh = fmaxf(__fadd_rn(__fsub_rn(yy2,yy1),1.0f), 0.0f);
    float inter = __fmul_rn(ww,hh);
    float iou = __fdiv_rn(inter, __fsub_rn(__fadd_rn(areaI, areaJ), inter));
    bool bit = jok && (jg > ig) && (iou > 0.7f);
    uint64_t wword = __ballot(bit);
    if (lane == 0) mrow[(size_t)ig*96 + jb] = wword;
  }
}

// ---------------- NMS: single-wave greedy scan over bit-matrix ----------------
__global__ __launch_bounds__(64) void nmsScanK(const float* __restrict__ rbox,
                                               const uint64_t* __restrict__ mask,
                                               float* __restrict__ out){
  const int b = blockIdx.x;
  const int lane = threadIdx.x;
  const uint64_t* mrow = &mask[(size_t)b*PRE_NMS_N*96];
  uint64_t s0 = 0ull, s1 = 0ull;
  int cnt = 0;
  for (int i=0; i<PRE_NMS_N; i++){
    int w = i >> 6;
    uint64_t sw = (w < 64) ? __shfl(s0, w) : __shfl(s1, w-64);
    if (!((sw >> (i & 63)) & 1ull)){
      if (lane == 0){
        const float* s = &rbox[((size_t)b*PRE_NMS_N + i)*4];
        float* o = &out[(size_t)(b*POST_NMS_N + cnt)*5];
        o[0] = (float)b; o[1]=s[0]; o[2]=s[1]; o[3]=s[2]; o[4]=s[3];
      }
      cnt++;
      if (cnt == POST_NMS_N) break;
      const uint64_t* mr = mrow + (size_t)i*96;
      s0 |= mr[lane];
      if (lane < 30) s1 |= mr[64+lane];
    }
  }
  for (int r = cnt + lane; r < POST_NMS_N; r += 64){
    float* o = &out[(size_t)(b*POST_NMS_N + r)*5];
    o[0] = (float)b; o[1]=0.f; o[2]=0.f; o[3]=0.f; o[4]=0.f;
  }
}

extern "C" void kernel_launch(void* const* d_in, const int* in_sizes, int n_in,
                              void* d_out, int out_size, void* d_ws, size_t ws_size,
                              hipStream_t stream) {
  const float* features = (const float*)d_in[0];
  const float* im_info  = (const float*)d_in[1];
  const float* W1 = (const float*)d_in[2];
  const float* b1 = (const float*)d_in[3];
  const float* Ws = (const float*)d_in[4];
  const float* bs = (const float*)d_in[5];
  const float* Wb = (const float*)d_in[6];
  const float* bb = (const float*)d_in[7];
  float* out = (float*)d_out;
  char* ws = (char*)d_ws;

  const size_t offX     = 0;                          // x (4,512,4096) — reused as NMS mask later
  const size_t offCls   = offX     + (size_t)4*512*4096*4;
  const size_t offBbox  = offCls   + (size_t)4*24*4096*4;
  const size_t offBoxes = offBbox  + (size_t)4*48*4096*4;
  const size_t offU     = offBoxes + (size_t)4*49152*4*4;
  const size_t offH1    = offU     + (size_t)4*49152*4;
  const size_t offH2    = offH1    + (size_t)4*65536*4;
  const size_t offCtr   = offH2    + (size_t)4*65536*4;
  const size_t offKHi   = offCtr   + 256;
  const size_t offKEq   = offKHi   + (size_t)4*8192*8;
  const size_t offRbox  = offKEq   + (size_t)4*8192*8;

  float*    x       = (float*)(ws + offX);
  float*    clsRaw  = (float*)(ws + offCls);
  float*    bboxRaw = (float*)(ws + offBbox);
  float*    boxes   = (float*)(ws + offBoxes);
  uint32_t* ubits   = (uint32_t*)(ws + offU);
  uint32_t* hist1   = (uint32_t*)(ws + offH1);
  uint32_t* hist2   = (uint32_t*)(ws + offH2);
  uint32_t* thrWS   = (uint32_t*)(ws + offCtr);       // 16 u32
  uint32_t* cnts    = thrWS + 16;                     // 8 u32
  uint64_t* keyHi   = (uint64_t*)(ws + offKHi);
  uint64_t* keyEq   = (uint64_t*)(ws + offKEq);
  float*    rbox    = (float*)(ws + offRbox);
  uint64_t* mask    = (uint64_t*)(ws + offX);         // aliases x (dead after conv1x1)

  // zero hist1+hist2+counters (contiguous region)
  {
    int nWords = (int)(((offCtr + 256) - offH1) / 4);
    int grid = (nWords + 255) / 256;
    zeroK<<<grid, 256, 0, stream>>>((uint32_t*)(ws + offH1), nWords);
  }
  conv3x3K<<<dim3(64, 4, 4), 256, 0, stream>>>(features, W1, b1, x);
  conv1x1K<<<256, 256, 0, stream>>>(x, Ws, bs, Wb, bb, clsRaw, bboxRaw);
  {
    int grid = (NBATCH*NANCH + 255) / 256;   // 768
    decodeK<<<grid, 256, 0, stream>>>(clsRaw, bboxRaw, im_info, boxes, ubits, hist1);
    selectK<<<4, 1024, 0, stream>>>(hist1, thrWS, 0);
    histLoK<<<grid, 256, 0, stream>>>(ubits, thrWS, hist2);
    selectK<<<4, 1024, 0, stream>>>(hist2, thrWS, 1);
    compactK<<<grid, 256, 0, stream>>>(ubits, thrWS, cnts, keyHi, keyEq);
  }
  sortGatherK<<<4, 1024, 0, stream>>>(keyHi, keyEq, cnts, boxes, rbox);
  nmsMaskK<<<dim3(94, 94, 4), 64, 0, stream>>>(rbox, mask);
  nmsScanK<<<4, 64, 0, stream>>>(rbox, mask, out);
}